// Round 1
// baseline (2665.087 us; speedup 1.0000x reference)
//
#include <hip/hip_runtime.h>
#include <cstdint>
#include <cstddef>

// ---------------------------------------------------------------------------
// ASD_RNN: enc GEMM + fused-gate LSTM + prototype-distance head. fp32 baseline.
// B=64, S=64, F_IN=2048, H=512, 4H=2048, P2=20.
// ---------------------------------------------------------------------------

// Transpose Wh [512][2048] (cols = gate*512+j) -> Wh_t[(k*512+j)*4 + gate]
__global__ __launch_bounds__(256) void k_transpose_wh(const float* __restrict__ Wh,
                                                      float* __restrict__ Wh_t) {
    int idx = blockIdx.x * 256 + threadIdx.x;      // 0..262143 = k*512+j
    int k = idx >> 9, j = idx & 511;
    float4 v;
    v.x = Wh[k * 2048 + 0 * 512 + j];
    v.y = Wh[k * 2048 + 1 * 512 + j];
    v.z = Wh[k * 2048 + 2 * 512 + j];
    v.w = Wh[k * 2048 + 3 * 512 + j];
    ((float4*)Wh_t)[idx] = v;
}

// Tiled fp32 GEMM C[M,N] = A[M,K] @ B[K,N], 64x64 tile, 4x4 per thread.
// mode 0: C=fuse: relu(acc + bias0[n]) + cat_emb[category[m>>6]*512 + n], store [m][n]
// mode 1: C=xg_t: acc + bias0[n] + bias1[n], scatter to [s][n][b] with m=b*64+s, N==2048
__global__ __launch_bounds__(256) void k_gemm(
    const float* __restrict__ A, const float* __restrict__ Bm,
    int M, int N, int K,
    const float* __restrict__ bias0, const float* __restrict__ bias1,
    const float* __restrict__ cat_emb, const int* __restrict__ category,
    float* __restrict__ C, int mode)
{
    __shared__ float As[16][68];   // [k][m]
    __shared__ float Bs[16][68];   // [k][n]
    const int tid = threadIdx.x;
    const int tx = tid & 15, ty = tid >> 4;
    const int m0 = blockIdx.y * 64, n0 = blockIdx.x * 64;
    const int ar = tid >> 2, ac4 = tid & 3;    // A loader
    const int br = tid >> 4, bc4 = tid & 15;   // B loader

    float acc[4][4] = {};

    for (int k0 = 0; k0 < K; k0 += 16) {
        float4 av = *(const float4*)(A + (size_t)(m0 + ar) * K + k0 + ac4 * 4);
        float4 bv = *(const float4*)(Bm + (size_t)(k0 + br) * N + n0 + bc4 * 4);
        __syncthreads();
        As[ac4 * 4 + 0][ar] = av.x;
        As[ac4 * 4 + 1][ar] = av.y;
        As[ac4 * 4 + 2][ar] = av.z;
        As[ac4 * 4 + 3][ar] = av.w;
        *(float4*)&Bs[br][bc4 * 4] = bv;
        __syncthreads();
#pragma unroll
        for (int k = 0; k < 16; ++k) {
            float4 a4 = *(const float4*)&As[k][ty * 4];
            float4 b4 = *(const float4*)&Bs[k][tx * 4];
            float a_[4] = {a4.x, a4.y, a4.z, a4.w};
            float b_[4] = {b4.x, b4.y, b4.z, b4.w};
#pragma unroll
            for (int i = 0; i < 4; ++i)
#pragma unroll
                for (int j = 0; j < 4; ++j)
                    acc[i][j] += a_[i] * b_[j];
        }
    }

    if (mode == 0) {
        const int cat = category[m0 >> 6];          // m>>6 constant per block
        const float* ce = cat_emb + cat * 512;
#pragma unroll
        for (int i = 0; i < 4; ++i) {
            int m = m0 + ty * 4 + i;
            int n = n0 + tx * 4;
            float4 r;
            r.x = fmaxf(acc[i][0] + bias0[n + 0], 0.f) + ce[n + 0];
            r.y = fmaxf(acc[i][1] + bias0[n + 1], 0.f) + ce[n + 1];
            r.z = fmaxf(acc[i][2] + bias0[n + 2], 0.f) + ce[n + 2];
            r.w = fmaxf(acc[i][3] + bias0[n + 3], 0.f) + ce[n + 3];
            *(float4*)(C + (size_t)m * N + n) = r;
        }
    } else {
#pragma unroll
        for (int i = 0; i < 4; ++i) {
            int m = m0 + ty * 4 + i;
            int s = m & 63, b = m >> 6;
#pragma unroll
            for (int jj = 0; jj < 4; ++jj) {
                int n = n0 + tx * 4 + jj;
                C[((size_t)s * 2048 + n) * 64 + b] = acc[i][jj] + bias0[n] + bias1[n];
            }
        }
    }
}

// One LSTM time step. grid=128 blocks (4 hidden units each), block=256 (lane=b, wave=j).
// xg_t: [2048][64] slice for this step. h layout transposed [j/k][b].
__global__ __launch_bounds__(256) void k_lstm_step(
    const float* __restrict__ xg_t, const float* __restrict__ Wh_t,
    const float* __restrict__ h_in, float* __restrict__ h_out,
    float* __restrict__ c_t)
{
    const int t = threadIdx.x;
    const int b = t & 63;
    const int jw = t >> 6;
    const int j = blockIdx.x * 4 + jw;
    const int ju = __builtin_amdgcn_readfirstlane(j);   // wave-uniform -> s_load for Wh
    const float4* __restrict__ wr = (const float4*)Wh_t + ju;

    float a0 = 0.f, a1 = 0.f, a2 = 0.f, a3 = 0.f;
#pragma unroll 4
    for (int k = 0; k < 512; ++k) {
        float hv = h_in[k * 64 + b];        // coalesced 256B row, L1/L2 hot
        float4 w = wr[(size_t)k * 512];     // wave-uniform -> scalar loads
        a0 += hv * w.x;
        a1 += hv * w.y;
        a2 += hv * w.z;
        a3 += hv * w.w;
    }
    float gi = a0 + xg_t[(0 * 512 + ju) * 64 + b];
    float gf = a1 + xg_t[(1 * 512 + ju) * 64 + b];
    float go = a2 + xg_t[(2 * 512 + ju) * 64 + b];
    float gg = a3 + xg_t[(3 * 512 + ju) * 64 + b];
    gi = 1.f / (1.f + expf(-gi));
    gf = 1.f / (1.f + expf(-gf));
    go = 1.f / (1.f + expf(-go));
    gg = tanhf(gg);
    float c = c_t[j * 64 + b];
    c = gf * c + gi * gg;
    float h = go * c;                        // NOTE: no tanh on c (matches reference)
    c_t[j * 64 + b] = c;
    h_out[j * 64 + b] = h;
}

// Prototype distances + gate logit. One block per (b,s).
__global__ __launch_bounds__(256) void k_dist(
    const float* __restrict__ v_feat, const float* __restrict__ proto,
    const float* __restrict__ W_dd, const float* __restrict__ W_gate,
    float* __restrict__ dd_logit, float* __restrict__ g_logit)
{
    __shared__ float vs[2048];
    __shared__ float red[4];
    const int bs = blockIdx.x;
    const int b = bs >> 6, s = bs & 63;
    const int wave = threadIdx.x >> 6, lane = threadIdx.x & 63;
    const float* vrow = v_feat + (size_t)bs * 2048;

    float gp = 0.f;
    for (int i = threadIdx.x; i < 2048; i += 256) {
        float x = vrow[i];
        vs[i] = x;
        gp += x * W_gate[i];
    }
#pragma unroll
    for (int o = 32; o > 0; o >>= 1) gp += __shfl_down(gp, o);
    if (lane == 0) red[wave] = gp;
    __syncthreads();   // also guards vs[]
    if (threadIdx.x == 0)
        atomicAdd(&g_logit[b], red[0] + red[1] + red[2] + red[3]);

    float ddp = 0.f;
    for (int p = wave; p < 20; p += 4) {
        const float* pr = proto + p * 2048;
        float d = 0.f;
        for (int f = lane; f < 2048; f += 64) {
            float df = vs[f] - pr[f];
            d += df * df;
        }
#pragma unroll
        for (int o = 32; o > 0; o >>= 1) d += __shfl_down(d, o);
        if (lane == 0) {
            float dist_feat = logf((d + 1.0f) / (d + 1e-8f));
            ddp += dist_feat * W_dd[s * 20 + p];
        }
    }
    if (lane == 0) atomicAdd(&dd_logit[b], ddp);
}

// Final combine: one wave, one thread per batch element.
__global__ __launch_bounds__(64) void k_final(
    const float* __restrict__ h_t, const float* __restrict__ W_dec,
    const float* __restrict__ b_dec, const float* __restrict__ dd_logit,
    const float* __restrict__ b_dd, const float* __restrict__ g_logit,
    const float* __restrict__ b_gate, float* __restrict__ out)
{
    int b = threadIdx.x;
    float acc = 0.f;
    for (int j = 0; j < 512; ++j) acc += h_t[j * 64 + b] * W_dec[j];
    float output = 1.f / (1.f + expf(-(acc + b_dec[0])));
    float gate   = 1.f / (1.f + expf(-(g_logit[b] * (1.0f / 64.f) + b_gate[0])));
    float ddp    = 1.f / (1.f + expf(-(dd_logit[b] + b_dd[0])));
    out[b] = output * gate + ddp * (1.f - gate);
}

extern "C" void kernel_launch(void* const* d_in, const int* in_sizes, int n_in,
                              void* d_out, int out_size, void* d_ws, size_t ws_size,
                              hipStream_t stream) {
    const float* v_feat   = (const float*)d_in[0];
    const int*   category = (const int*)d_in[1];
    const float* W_enc    = (const float*)d_in[2];
    const float* b_enc    = (const float*)d_in[3];
    const float* Wx       = (const float*)d_in[4];
    const float* bx       = (const float*)d_in[5];
    const float* Wh       = (const float*)d_in[6];
    const float* bh       = (const float*)d_in[7];
    const float* cat_emb  = (const float*)d_in[8];
    const float* W_dec    = (const float*)d_in[9];
    const float* b_dec    = (const float*)d_in[10];
    const float* proto    = (const float*)d_in[11];
    const float* W_dd     = (const float*)d_in[12];
    const float* b_dd     = (const float*)d_in[13];
    const float* W_gate   = (const float*)d_in[14];
    const float* b_gate   = (const float*)d_in[15];
    float* out = (float*)d_out;

    char* ws = (char*)d_ws;
    float* fuse     = (float*)(ws + 0);           // 4096*512*4   = 8 MB
    float* xg_t     = (float*)(ws + 8388608);     // 64*2048*64*4 = 32 MB  [s][n][b]
    float* Wh_t     = (float*)(ws + 41943040);    // 4 MB
    float* h_t      = (float*)(ws + 46137344);    // 2*512*64*4 = 256 KB (ping-pong)
    float* c_t      = (float*)(ws + 46399488);    // 128 KB
    float* dd_logit = (float*)(ws + 46530560);    // 256 B
    float* g_logit  = (float*)(ws + 46530816);    // 256 B

    // zero h (both buffers), c, and logits in one contiguous memset
    hipMemsetAsync(h_t, 0, 393728, stream);

    k_transpose_wh<<<1024, 256, 0, stream>>>(Wh, Wh_t);
    k_gemm<<<dim3(8, 64), 256, 0, stream>>>(v_feat, W_enc, 4096, 512, 2048,
                                            b_enc, nullptr, cat_emb, category, fuse, 0);
    k_gemm<<<dim3(32, 64), 256, 0, stream>>>(fuse, Wx, 4096, 2048, 512,
                                             bx, bh, nullptr, nullptr, xg_t, 1);
    for (int s = 0; s < 64; ++s) {
        const float* h_in = h_t + (s & 1) * 32768;
        float* h_out      = h_t + ((s + 1) & 1) * 32768;
        k_lstm_step<<<128, 256, 0, stream>>>(xg_t + (size_t)s * 131072, Wh_t,
                                             h_in, h_out, c_t);
    }
    k_dist<<<4096, 256, 0, stream>>>(v_feat, proto, W_dd, W_gate, dd_logit, g_logit);
    k_final<<<1, 64, 0, stream>>>(h_t, W_dec, b_dec, dd_logit, b_dd, g_logit, b_gate, out);
}

// Round 2
// 2368.085 us; speedup vs baseline: 1.1254x; 1.1254x over previous
//
#include <hip/hip_runtime.h>
#include <cstdint>
#include <cstddef>

// ---------------------------------------------------------------------------
// ASD_RNN round 2: bf16-MFMA GEMMs + dot-product-decomposed dist head.
// B=64, S=64, F_IN=2048, H=512, 4H=2048, P2=20.
// ---------------------------------------------------------------------------

typedef __attribute__((ext_vector_type(8))) short short8;
typedef __attribute__((ext_vector_type(4))) float f32x4;

__device__ __forceinline__ ushort f2bf(float x) {
    uint32_t u = __float_as_uint(x);
    uint32_t r = (u + 0x7FFF + ((u >> 16) & 1)) >> 16;   // RNE
    return (ushort)r;
}

// fp32 -> bf16 elementwise (4 elems/thread)
__global__ __launch_bounds__(256) void k_f32_to_bf16(const float* __restrict__ in,
                                                     ushort* __restrict__ out) {
    int i = blockIdx.x * 256 + threadIdx.x;
    float4 v = ((const float4*)in)[i];
    ushort4 o;
    o.x = f2bf(v.x); o.y = f2bf(v.y); o.z = f2bf(v.z); o.w = f2bf(v.w);
    ((ushort4*)out)[i] = o;
}

// in [R][C] fp32 -> out [C][R] bf16, 32x32 LDS tiles. grid (C/32, R/32)
__global__ __launch_bounds__(256) void k_transpose_bf16(const float* __restrict__ in,
                                                        ushort* __restrict__ out,
                                                        int R, int C) {
    __shared__ float t[32][33];
    int r0 = blockIdx.y * 32, c0 = blockIdx.x * 32;
    int rr = threadIdx.x >> 3, cc = (threadIdx.x & 7) * 4;
    float4 v = *(const float4*)(in + (size_t)(r0 + rr) * C + c0 + cc);
    t[rr][cc + 0] = v.x; t[rr][cc + 1] = v.y; t[rr][cc + 2] = v.z; t[rr][cc + 3] = v.w;
    __syncthreads();
    ushort4 o;
    o.x = f2bf(t[cc + 0][rr]);
    o.y = f2bf(t[cc + 1][rr]);
    o.z = f2bf(t[cc + 2][rr]);
    o.w = f2bf(t[cc + 3][rr]);
    *(ushort4*)(out + (size_t)(c0 + rr) * R + r0 + cc) = o;
}

// Transpose Wh [512][2048] (cols = gate*512+j) -> Wh_t[(k*512+j)*4 + gate] fp32
__global__ __launch_bounds__(256) void k_transpose_wh(const float* __restrict__ Wh,
                                                      float* __restrict__ Wh_t) {
    int idx = blockIdx.x * 256 + threadIdx.x;      // 0..262143 = k*512+j
    int k = idx >> 9, j = idx & 511;
    float4 v;
    v.x = Wh[k * 2048 + 0 * 512 + j];
    v.y = Wh[k * 2048 + 1 * 512 + j];
    v.z = Wh[k * 2048 + 2 * 512 + j];
    v.w = Wh[k * 2048 + 3 * 512 + j];
    ((float4*)Wh_t)[idx] = v;
}

// bf16 MFMA GEMM: C[M,N] = A[M,K] @ Bt[N,K]^T. 128x128 tile, 4 waves of 64x64,
// each wave 4x4 grid of 16x16x32 MFMA tiles.
// mode 0: fuse (bf16 [M][512]) = relu(acc+bias0[n]) + cat_emb[category[m>>6]][n]
// mode 1: xg_t (fp32 [s][2048][b]) = acc + bias0[n] + bias1[n], m = b*64+s
__global__ __launch_bounds__(256) void k_gemm_mfma(
    const ushort* __restrict__ A, const ushort* __restrict__ Bt,
    int M, int N, int K,
    const float* __restrict__ bias0, const float* __restrict__ bias1,
    const float* __restrict__ cat_emb, const int* __restrict__ category,
    void* __restrict__ Cout, int mode)
{
    __shared__ ushort As[128][40];   // +8 pad: rows 0 and 8 alias -> 2-way (free)
    __shared__ ushort Bs[128][40];
    const int tid = threadIdx.x;
    const int lane = tid & 63, w = tid >> 6;
    const int quad = lane >> 4, l16 = lane & 15;
    const int m0 = blockIdx.y * 128, n0 = blockIdx.x * 128;
    const int wm = (w & 1) * 64, wn = (w >> 1) * 64;

    f32x4 acc[4][4] = {};

    const int lr = tid >> 2;          // 0..63: row group for staging
    const int lc = (tid & 3) * 8;     // k-element offset (8 bf16 = 16B)

    for (int k0 = 0; k0 < K; k0 += 32) {
        uint4 a0 = *(const uint4*)(A + (size_t)(m0 + lr) * K + k0 + lc);
        uint4 a1 = *(const uint4*)(A + (size_t)(m0 + 64 + lr) * K + k0 + lc);
        uint4 b0 = *(const uint4*)(Bt + (size_t)(n0 + lr) * K + k0 + lc);
        uint4 b1 = *(const uint4*)(Bt + (size_t)(n0 + 64 + lr) * K + k0 + lc);
        __syncthreads();
        *(uint4*)&As[lr][lc] = a0;
        *(uint4*)&As[64 + lr][lc] = a1;
        *(uint4*)&Bs[lr][lc] = b0;
        *(uint4*)&Bs[64 + lr][lc] = b1;
        __syncthreads();
        short8 af[4], bf[4];
#pragma unroll
        for (int i = 0; i < 4; ++i) af[i] = *(const short8*)&As[wm + i * 16 + l16][quad * 8];
#pragma unroll
        for (int j = 0; j < 4; ++j) bf[j] = *(const short8*)&Bs[wn + j * 16 + l16][quad * 8];
#pragma unroll
        for (int i = 0; i < 4; ++i)
#pragma unroll
            for (int j = 0; j < 4; ++j)
                acc[i][j] = __builtin_amdgcn_mfma_f32_16x16x32_bf16(af[i], bf[j], acc[i][j], 0, 0, 0);
    }

    if (mode == 0) {
        ushort* C = (ushort*)Cout;
#pragma unroll
        for (int i = 0; i < 4; ++i) {
            int mbase = m0 + wm + i * 16 + quad * 4;
#pragma unroll
            for (int r = 0; r < 4; ++r) {
                int m = mbase + r;
                const float* ce = cat_emb + category[m >> 6] * 512;
#pragma unroll
                for (int j = 0; j < 4; ++j) {
                    int n = n0 + wn + j * 16 + l16;
                    float v = fmaxf(acc[i][j][r] + bias0[n], 0.f) + ce[n];
                    C[(size_t)m * 512 + n] = f2bf(v);
                }
            }
        }
    } else {
        float* C = (float*)Cout;
#pragma unroll
        for (int i = 0; i < 4; ++i) {
            int mbase = m0 + wm + i * 16 + quad * 4;
#pragma unroll
            for (int r = 0; r < 4; ++r) {
                int m = mbase + r;
                int s = m & 63, b = m >> 6;
#pragma unroll
                for (int j = 0; j < 4; ++j) {
                    int n = n0 + wn + j * 16 + l16;
                    C[((size_t)s * 2048 + n) * 64 + b] = acc[i][j][r] + bias0[n] + bias1[n];
                }
            }
        }
    }
}

// One LSTM time step. grid=128 blocks (4 j's each), block=256 (lane=b, wave=j).
__global__ __launch_bounds__(256) void k_lstm_step(
    const float* __restrict__ xg_t, const float* __restrict__ Wh_t,
    const float* __restrict__ h_in, float* __restrict__ h_out,
    float* __restrict__ c_t)
{
    const int t = threadIdx.x;
    const int b = t & 63;
    const int jw = t >> 6;
    const int j = blockIdx.x * 4 + jw;
    const int ju = __builtin_amdgcn_readfirstlane(j);   // wave-uniform -> s_load for Wh
    const float4* __restrict__ wr = (const float4*)Wh_t + ju;

    float a0 = 0.f, a1 = 0.f, a2 = 0.f, a3 = 0.f;
#pragma unroll 4
    for (int k = 0; k < 512; ++k) {
        float hv = h_in[k * 64 + b];
        float4 w = wr[(size_t)k * 512];
        a0 += hv * w.x;
        a1 += hv * w.y;
        a2 += hv * w.z;
        a3 += hv * w.w;
    }
    float gi = a0 + xg_t[(0 * 512 + ju) * 64 + b];
    float gf = a1 + xg_t[(1 * 512 + ju) * 64 + b];
    float go = a2 + xg_t[(2 * 512 + ju) * 64 + b];
    float gg = a3 + xg_t[(3 * 512 + ju) * 64 + b];
    gi = 1.f / (1.f + expf(-gi));
    gf = 1.f / (1.f + expf(-gf));
    go = 1.f / (1.f + expf(-go));
    gg = tanhf(gg);
    float c = c_t[j * 64 + b];
    c = gf * c + gi * gg;
    float h = go * c;                        // no tanh on c (matches reference)
    c_t[j * 64 + b] = c;
    h_out[j * 64 + b] = h;
}

// dist via |v|^2 - 2 v.p + |p|^2. One block per 4 (b,s) rows (same b).
__global__ __launch_bounds__(256) void k_dist2(
    const float* __restrict__ v_feat, const float* __restrict__ proto,
    const float* __restrict__ W_dd, const float* __restrict__ W_gate,
    float* __restrict__ dd_logit, float* __restrict__ g_logit)
{
    __shared__ float vs[4][2048];
    __shared__ float redn[4][4];   // [wave][row]
    __shared__ float redg[4];
    __shared__ float n2s[4];
    const int bs0 = blockIdx.x * 4;
    const int b = bs0 >> 6;
    const int s0 = bs0 & 63;
    const int tid = threadIdx.x, lane = tid & 63, wv = tid >> 6;

    float4 wg0 = ((const float4*)W_gate)[tid * 2];
    float4 wg1 = ((const float4*)W_gate)[tid * 2 + 1];
    float gp = 0.f;
#pragma unroll
    for (int r = 0; r < 4; ++r) {
        const float* vr = v_feat + (size_t)(bs0 + r) * 2048;
        float4 x0 = ((const float4*)vr)[tid * 2];
        float4 x1 = ((const float4*)vr)[tid * 2 + 1];
        *(float4*)&vs[r][tid * 8] = x0;
        *(float4*)&vs[r][tid * 8 + 4] = x1;
        float n2 = x0.x * x0.x + x0.y * x0.y + x0.z * x0.z + x0.w * x0.w
                 + x1.x * x1.x + x1.y * x1.y + x1.z * x1.z + x1.w * x1.w;
        gp += x0.x * wg0.x + x0.y * wg0.y + x0.z * wg0.z + x0.w * wg0.w
            + x1.x * wg1.x + x1.y * wg1.y + x1.z * wg1.z + x1.w * wg1.w;
#pragma unroll
        for (int o = 32; o > 0; o >>= 1) n2 += __shfl_down(n2, o);
        if (lane == 0) redn[wv][r] = n2;
    }
#pragma unroll
    for (int o = 32; o > 0; o >>= 1) gp += __shfl_down(gp, o);
    if (lane == 0) redg[wv] = gp;
    __syncthreads();
    if (tid == 0) atomicAdd(&g_logit[b], redg[0] + redg[1] + redg[2] + redg[3]);
    if (tid < 4) n2s[tid] = redn[0][tid] + redn[1][tid] + redn[2][tid] + redn[3][tid];
    __syncthreads();

    float ddacc = 0.f;
    for (int p = wv; p < 20; p += 4) {
        const float* pr = proto + p * 2048;
        float d0 = 0.f, d1 = 0.f, d2 = 0.f, d3 = 0.f, pp2 = 0.f;
        for (int f = lane; f < 2048; f += 64) {
            float pv = pr[f];
            pp2 += pv * pv;
            d0 += pv * vs[0][f];
            d1 += pv * vs[1][f];
            d2 += pv * vs[2][f];
            d3 += pv * vs[3][f];
        }
#pragma unroll
        for (int o = 32; o > 0; o >>= 1) {
            d0 += __shfl_down(d0, o);
            d1 += __shfl_down(d1, o);
            d2 += __shfl_down(d2, o);
            d3 += __shfl_down(d3, o);
            pp2 += __shfl_down(pp2, o);
        }
        if (lane == 0) {
            float dr[4] = {d0, d1, d2, d3};
#pragma unroll
            for (int r = 0; r < 4; ++r) {
                float dist = n2s[r] - 2.f * dr[r] + pp2;
                float df = logf((dist + 1.0f) / (dist + 1e-8f));
                ddacc += df * W_dd[(s0 + r) * 20 + p];
            }
        }
    }
    if (lane == 0) atomicAdd(&dd_logit[b], ddacc);
}

// Final combine: one thread per batch element.
__global__ __launch_bounds__(64) void k_final(
    const float* __restrict__ h_t, const float* __restrict__ W_dec,
    const float* __restrict__ b_dec, const float* __restrict__ dd_logit,
    const float* __restrict__ b_dd, const float* __restrict__ g_logit,
    const float* __restrict__ b_gate, float* __restrict__ out)
{
    int b = threadIdx.x;
    float acc = 0.f;
    for (int j = 0; j < 512; ++j) acc += h_t[j * 64 + b] * W_dec[j];
    float output = 1.f / (1.f + expf(-(acc + b_dec[0])));
    float gate   = 1.f / (1.f + expf(-(g_logit[b] * (1.0f / 64.f) + b_gate[0])));
    float ddp    = 1.f / (1.f + expf(-(dd_logit[b] + b_dd[0])));
    out[b] = output * gate + ddp * (1.f - gate);
}

extern "C" void kernel_launch(void* const* d_in, const int* in_sizes, int n_in,
                              void* d_out, int out_size, void* d_ws, size_t ws_size,
                              hipStream_t stream) {
    const float* v_feat   = (const float*)d_in[0];
    const int*   category = (const int*)d_in[1];
    const float* W_enc    = (const float*)d_in[2];
    const float* b_enc    = (const float*)d_in[3];
    const float* Wx       = (const float*)d_in[4];
    const float* bx       = (const float*)d_in[5];
    const float* Wh       = (const float*)d_in[6];
    const float* bh       = (const float*)d_in[7];
    const float* cat_emb  = (const float*)d_in[8];
    const float* W_dec    = (const float*)d_in[9];
    const float* b_dec    = (const float*)d_in[10];
    const float* proto    = (const float*)d_in[11];
    const float* W_dd     = (const float*)d_in[12];
    const float* b_dd     = (const float*)d_in[13];
    const float* W_gate   = (const float*)d_in[14];
    const float* b_gate   = (const float*)d_in[15];
    float* out = (float*)d_out;

    char* ws = (char*)d_ws;
    float*  xg_t     = (float*)(ws + 0);           // 32 MB  [s][n][b]
    ushort* v_bf16   = (ushort*)(ws + 0);          // 16 MB (overlaps xg_t; dead before GEMM2)
    ushort* fuse     = (ushort*)(ws + 33554432);   // 4 MB bf16 [4096][512]
    float*  Wh_t     = (float*)(ws + 37748736);    // 4 MB
    ushort* Wenc_t   = (ushort*)(ws + 41943040);   // 2 MB bf16 [512][2048]
    ushort* Wx_t     = (ushort*)(ws + 44040192);   // 2 MB bf16 [2048][512]
    float*  h_t      = (float*)(ws + 46137344);    // 2*512*64*4 = 256 KB ping-pong
    float*  c_t      = (float*)(ws + 46399488);    // 128 KB
    float*  dd_logit = (float*)(ws + 46530560);    // 256 B
    float*  g_logit  = (float*)(ws + 46530816);    // 256 B

    // zero h (both buffers), c, dd_logit, g_logit in one memset
    hipMemsetAsync(h_t, 0, 393728, stream);

    k_f32_to_bf16<<<8192, 256, 0, stream>>>(v_feat, v_bf16);                 // 4096*2048
    k_transpose_bf16<<<dim3(16, 64), 256, 0, stream>>>(W_enc, Wenc_t, 2048, 512);
    k_transpose_bf16<<<dim3(64, 16), 256, 0, stream>>>(Wx, Wx_t, 512, 2048);
    k_transpose_wh<<<1024, 256, 0, stream>>>(Wh, Wh_t);

    k_gemm_mfma<<<dim3(4, 32), 256, 0, stream>>>(v_bf16, Wenc_t, 4096, 512, 2048,
                                                 b_enc, nullptr, cat_emb, category,
                                                 fuse, 0);
    k_gemm_mfma<<<dim3(16, 32), 256, 0, stream>>>(fuse, Wx_t, 4096, 2048, 512,
                                                  bx, bh, nullptr, nullptr,
                                                  xg_t, 1);

    for (int s = 0; s < 64; ++s) {
        const float* h_in = h_t + (s & 1) * 32768;
        float* h_out      = h_t + ((s + 1) & 1) * 32768;
        k_lstm_step<<<128, 256, 0, stream>>>(xg_t + (size_t)s * 131072, Wh_t,
                                             h_in, h_out, c_t);
    }

    k_dist2<<<1024, 256, 0, stream>>>(v_feat, proto, W_dd, W_gate, dd_logit, g_logit);
    k_final<<<1, 64, 0, stream>>>(h_t, W_dec, b_dec, dd_logit, b_dd, g_logit, b_gate, out);
}

// Round 3
// 762.861 us; speedup vs baseline: 3.4935x; 3.1042x over previous
//
#include <hip/hip_runtime.h>
#include <cstdint>
#include <cstddef>

// ---------------------------------------------------------------------------
// ASD_RNN round 3: persistent-grid LSTM (Wh in LDS, device barrier per step),
// MFMA-decomposed prototype-distance head, bf16 MFMA GEMMs.
// B=64, S=64, F_IN=2048, H=512, 4H=2048, P2=20.
// ---------------------------------------------------------------------------

typedef __attribute__((ext_vector_type(8))) short short8;
typedef __attribute__((ext_vector_type(4))) float f32x4;

__device__ __forceinline__ ushort f2bf(float x) {
    uint32_t u = __float_as_uint(x);
    uint32_t r = (u + 0x7FFF + ((u >> 16) & 1)) >> 16;   // RNE
    return (ushort)r;
}
__device__ __forceinline__ float bf2f(ushort u) {
    return __uint_as_float(((uint32_t)u) << 16);
}
__device__ __forceinline__ float sigm(float x) { return 1.f / (1.f + expf(-x)); }

// fp32 -> bf16 elementwise (4 elems/thread)
__global__ __launch_bounds__(256) void k_f32_to_bf16(const float* __restrict__ in,
                                                     ushort* __restrict__ out) {
    int i = blockIdx.x * 256 + threadIdx.x;
    float4 v = ((const float4*)in)[i];
    ushort4 o;
    o.x = f2bf(v.x); o.y = f2bf(v.y); o.z = f2bf(v.z); o.w = f2bf(v.w);
    ((ushort4*)out)[i] = o;
}

// in [R][C] fp32 -> out [C][R] bf16, 32x32 LDS tiles. grid (C/32, R/32)
// remap!=0: output row n is remapped to ((n&511)<<2)|(n>>9)  (j*4+gate order)
__global__ __launch_bounds__(256) void k_transpose_bf16(const float* __restrict__ in,
                                                        ushort* __restrict__ out,
                                                        int R, int C, int remap) {
    __shared__ float t[32][33];
    int r0 = blockIdx.y * 32, c0 = blockIdx.x * 32;
    int rr = threadIdx.x >> 3, cc = (threadIdx.x & 7) * 4;
    float4 v = *(const float4*)(in + (size_t)(r0 + rr) * C + c0 + cc);
    t[rr][cc + 0] = v.x; t[rr][cc + 1] = v.y; t[rr][cc + 2] = v.z; t[rr][cc + 3] = v.w;
    __syncthreads();
    ushort4 o;
    o.x = f2bf(t[cc + 0][rr]);
    o.y = f2bf(t[cc + 1][rr]);
    o.z = f2bf(t[cc + 2][rr]);
    o.w = f2bf(t[cc + 3][rr]);
    int n = c0 + rr;
    int np = remap ? (((n & 511) << 2) | (n >> 9)) : n;
    *(ushort4*)(out + (size_t)np * R + r0 + cc) = o;
}

// bf16 MFMA GEMM: C[M,N] = A[M,K] @ Bt[N,K]^T. 128x128 tile, 4 waves of 64x64.
// mode 0: fuse (bf16 [M][512]) = relu(acc+bias0[n]) + cat_emb[category[m>>6]][n]
// mode 1: xg (fp32 [s][b][n']) = acc + bias0[n] + bias1[n]; m=b*64+s, n'=(n&511)*4+(n>>9)
__global__ __launch_bounds__(256) void k_gemm_mfma(
    const ushort* __restrict__ A, const ushort* __restrict__ Bt,
    int M, int N, int K,
    const float* __restrict__ bias0, const float* __restrict__ bias1,
    const float* __restrict__ cat_emb, const int* __restrict__ category,
    void* __restrict__ Cout, int mode)
{
    __shared__ ushort As[128][40];
    __shared__ ushort Bs[128][40];
    const int tid = threadIdx.x;
    const int lane = tid & 63, w = tid >> 6;
    const int quad = lane >> 4, l16 = lane & 15;
    const int m0 = blockIdx.y * 128, n0 = blockIdx.x * 128;
    const int wm = (w & 1) * 64, wn = (w >> 1) * 64;

    f32x4 acc[4][4] = {};
    const int lr = tid >> 2;
    const int lc = (tid & 3) * 8;

    for (int k0 = 0; k0 < K; k0 += 32) {
        uint4 a0 = *(const uint4*)(A + (size_t)(m0 + lr) * K + k0 + lc);
        uint4 a1 = *(const uint4*)(A + (size_t)(m0 + 64 + lr) * K + k0 + lc);
        uint4 b0 = *(const uint4*)(Bt + (size_t)(n0 + lr) * K + k0 + lc);
        uint4 b1 = *(const uint4*)(Bt + (size_t)(n0 + 64 + lr) * K + k0 + lc);
        __syncthreads();
        *(uint4*)&As[lr][lc] = a0;
        *(uint4*)&As[64 + lr][lc] = a1;
        *(uint4*)&Bs[lr][lc] = b0;
        *(uint4*)&Bs[64 + lr][lc] = b1;
        __syncthreads();
        short8 af[4], bf[4];
#pragma unroll
        for (int i = 0; i < 4; ++i) af[i] = *(const short8*)&As[wm + i * 16 + l16][quad * 8];
#pragma unroll
        for (int j = 0; j < 4; ++j) bf[j] = *(const short8*)&Bs[wn + j * 16 + l16][quad * 8];
#pragma unroll
        for (int i = 0; i < 4; ++i)
#pragma unroll
            for (int j = 0; j < 4; ++j)
                acc[i][j] = __builtin_amdgcn_mfma_f32_16x16x32_bf16(af[i], bf[j], acc[i][j], 0, 0, 0);
    }

    if (mode == 0) {
        ushort* C = (ushort*)Cout;
#pragma unroll
        for (int i = 0; i < 4; ++i) {
            int mbase = m0 + wm + i * 16 + quad * 4;
#pragma unroll
            for (int r = 0; r < 4; ++r) {
                int m = mbase + r;
                const float* ce = cat_emb + category[m >> 6] * 512;
#pragma unroll
                for (int j = 0; j < 4; ++j) {
                    int n = n0 + wn + j * 16 + l16;
                    float v = fmaxf(acc[i][j][r] + bias0[n], 0.f) + ce[n];
                    C[(size_t)m * 512 + n] = f2bf(v);
                }
            }
        }
    } else {
        float* C = (float*)Cout;
#pragma unroll
        for (int i = 0; i < 4; ++i) {
            int mbase = m0 + wm + i * 16 + quad * 4;
#pragma unroll
            for (int r = 0; r < 4; ++r) {
                int m = mbase + r;
                int s = m & 63, b = m >> 6;
#pragma unroll
                for (int j = 0; j < 4; ++j) {
                    int n = n0 + wn + j * 16 + l16;
                    int np = ((n & 511) << 2) | (n >> 9);
                    C[((size_t)(s * 64 + b)) * 2048 + np] = acc[i][j][r] + bias0[n] + bias1[n];
                }
            }
        }
    }
}

// dots[bs][p] = v_bf16[bs][:] . proto_bf[p][:]  (proto_bf padded to 32 rows, rows>=20 zero)
// grid 64 blocks, block = 4 waves x 16 rows.
__global__ __launch_bounds__(256) void k_dot(const ushort* __restrict__ v_bf,
                                             const ushort* __restrict__ proto_bf,
                                             float* __restrict__ dots)
{
    const int tid = threadIdx.x;
    const int lane = tid & 63, w = tid >> 6;
    const int quad = lane >> 4, l16 = lane & 15;
    const int r0 = blockIdx.x * 64 + w * 16;

    f32x4 acc[2] = {};
    const ushort* arow = v_bf + (size_t)(r0 + l16) * 2048 + quad * 8;
    const ushort* b0p = proto_bf + (size_t)l16 * 2048 + quad * 8;
    const ushort* b1p = proto_bf + (size_t)(16 + l16) * 2048 + quad * 8;
#pragma unroll 8
    for (int kk = 0; kk < 64; ++kk) {
        short8 af = *(const short8*)(arow + kk * 32);
        short8 bf0 = *(const short8*)(b0p + kk * 32);
        short8 bf1 = *(const short8*)(b1p + kk * 32);
        acc[0] = __builtin_amdgcn_mfma_f32_16x16x32_bf16(af, bf0, acc[0], 0, 0, 0);
        acc[1] = __builtin_amdgcn_mfma_f32_16x16x32_bf16(af, bf1, acc[1], 0, 0, 0);
    }
#pragma unroll
    for (int t = 0; t < 2; ++t)
#pragma unroll
        for (int r = 0; r < 4; ++r)
            dots[(size_t)(r0 + quad * 4 + r) * 32 + t * 16 + l16] = acc[t][r];
}

// per-row |v|^2 and gate-logit partials. grid 1024 blocks x 4 rows.
__global__ __launch_bounds__(256) void k_rowstats(const float* __restrict__ v_feat,
                                                  const float* __restrict__ W_gate,
                                                  float* __restrict__ n2,
                                                  float* __restrict__ g_logit)
{
    const int lane = threadIdx.x & 63, w = threadIdx.x >> 6;
    const int bs = blockIdx.x * 4 + w;
    const float* vr = v_feat + (size_t)bs * 2048;
    float a = 0.f, g = 0.f;
#pragma unroll
    for (int i = 0; i < 8; ++i) {
        float4 x = ((const float4*)vr)[i * 64 + lane];
        float4 wg = ((const float4*)W_gate)[i * 64 + lane];
        a += x.x * x.x + x.y * x.y + x.z * x.z + x.w * x.w;
        g += x.x * wg.x + x.y * wg.y + x.z * wg.z + x.w * wg.w;
    }
#pragma unroll
    for (int o = 32; o > 0; o >>= 1) { a += __shfl_down(a, o); g += __shfl_down(g, o); }
    if (lane == 0) {
        n2[bs] = a;
        atomicAdd(&g_logit[bs >> 6], g);
    }
}

// p2[p] = |proto[p]|^2. grid 20 blocks x 64 threads.
__global__ __launch_bounds__(64) void k_p2(const float* __restrict__ proto,
                                           float* __restrict__ p2)
{
    const int lane = threadIdx.x;
    const float* pr = proto + (size_t)blockIdx.x * 2048;
    float a = 0.f;
#pragma unroll
    for (int i = 0; i < 8; ++i) {
        float4 x = ((const float4*)pr)[i * 64 + lane];
        a += x.x * x.x + x.y * x.y + x.z * x.z + x.w * x.w;
    }
#pragma unroll
    for (int o = 32; o > 0; o >>= 1) a += __shfl_down(a, o);
    if (lane == 0) p2[blockIdx.x] = a;
}

// dd_logit[b] = sum_{s,p} log((d+1)/(d+1e-8)) * W_dd[s*20+p]. grid 64 blocks.
__global__ __launch_bounds__(256) void k_dd(const float* __restrict__ dots,
                                            const float* __restrict__ n2,
                                            const float* __restrict__ p2,
                                            const float* __restrict__ W_dd,
                                            float* __restrict__ dd_logit)
{
    __shared__ float red[4];
    const int b = blockIdx.x;
    const int tid = threadIdx.x, lane = tid & 63, w = tid >> 6;
    float acc = 0.f;
    for (int u = tid; u < 1280; u += 256) {
        int s = u / 20, p = u - s * 20;
        int bs = b * 64 + s;
        float d = n2[bs] - 2.f * dots[(size_t)bs * 32 + p] + p2[p];
        acc += logf((d + 1.0f) / (d + 1e-8f)) * W_dd[s * 20 + p];
    }
#pragma unroll
    for (int o = 32; o > 0; o >>= 1) acc += __shfl_down(acc, o);
    if (lane == 0) red[w] = acc;
    __syncthreads();
    if (tid == 0) dd_logit[b] = red[0] + red[1] + red[2] + red[3];
}

// ---------------------------------------------------------------------------
// Persistent LSTM: 64 blocks x 256 threads. Block bn owns j in [bn*8, bn*8+8)
// (32 gate columns n' = j*4+g), Wh slice resident in LDS, c in registers.
// One device-scope barrier per step; ends with the decoder/combine head.
// ---------------------------------------------------------------------------
__device__ __forceinline__ void gbar(int* cnt, int nblk) {
    __syncthreads();
    if (threadIdx.x == 0) {
        __hip_atomic_fetch_add(cnt, 1, __ATOMIC_ACQ_REL, __HIP_MEMORY_SCOPE_AGENT);
        while (__hip_atomic_load(cnt, __ATOMIC_ACQUIRE, __HIP_MEMORY_SCOPE_AGENT) < nblk) {}
    }
    __syncthreads();
}

__global__ __launch_bounds__(256) void k_lstm_persist(
    const float* __restrict__ xg,        // [s][b][n'] fp32
    const ushort* __restrict__ Whr,      // [n'=2048][k=512] bf16
    ushort* __restrict__ h0,             // [b][j] bf16 ping (pre-zeroed)
    ushort* __restrict__ h1,             // pong
    int* __restrict__ cnt,               // [64+] pre-zeroed
    const float* __restrict__ W_dec, const float* __restrict__ b_dec,
    const float* __restrict__ dd_logit, const float* __restrict__ b_dd,
    const float* __restrict__ g_logit, const float* __restrict__ b_gate,
    float* __restrict__ out)
{
    __shared__ ushort Bs[32][520];       // 33.3 KB weights (row pad -> 2-way conflicts only)
    __shared__ float gl[4][16][33];      // 8.4 KB gate staging
    const int tid = threadIdx.x;
    const int lane = tid & 63, w = tid >> 6;
    const int quad = lane >> 4, l16 = lane & 15;
    const int bn = blockIdx.x;
    const int n0 = bn * 32;

    // stage this block's 32 weight rows (once)
    for (int c = tid; c < 2048; c += 256) {
        int row = c >> 6, chunk = c & 63;
        *(uint4*)&Bs[row][chunk * 8] = *(const uint4*)(Whr + (size_t)(n0 + row) * 512 + chunk * 8);
    }
    __syncthreads();

    float creg[2] = {0.f, 0.f};
    const int b_glob = w * 16 + l16;

    for (int s = 0; s < 64; ++s) {
        const ushort* hin = (s & 1) ? h1 : h0;
        ushort* hout = (s & 1) ? h0 : h1;

        f32x4 acc0 = {}, acc1 = {};
        const ushort* arow = hin + (size_t)b_glob * 512 + quad * 8;
#pragma unroll
        for (int kk = 0; kk < 16; ++kk) {
            short8 af = *(const short8*)(arow + kk * 32);
            short8 bf0 = *(const short8*)&Bs[l16][kk * 32 + quad * 8];
            short8 bf1 = *(const short8*)&Bs[16 + l16][kk * 32 + quad * 8];
            acc0 = __builtin_amdgcn_mfma_f32_16x16x32_bf16(af, bf0, acc0, 0, 0, 0);
            acc1 = __builtin_amdgcn_mfma_f32_16x16x32_bf16(af, bf1, acc1, 0, 0, 0);
        }
        // D layout: row=quad*4+r (b offset in wave), col=l16 (n' offset). Same-wave
        // LDS round-trip to regroup the 4 gates of each j into one lane.
#pragma unroll
        for (int r = 0; r < 4; ++r) {
            gl[w][quad * 4 + r][l16] = acc0[r];
            gl[w][quad * 4 + r][16 + l16] = acc1[r];
        }
        // no __syncthreads needed: gl[w] is written and read by wave w only
#pragma unroll
        for (int t = 0; t < 2; ++t) {
            int j_loc = (lane >> 4) + t * 4;
            float4 g4 = *(const float4*)&gl[w][l16][j_loc * 4];
            float4 xv = *(const float4*)(xg + ((size_t)(s * 64 + b_glob)) * 2048 + n0 + j_loc * 4);
            float gi = sigm(g4.x + xv.x);
            float gf = sigm(g4.y + xv.y);
            float go = sigm(g4.z + xv.z);
            float gg = tanhf(g4.w + xv.w);
            float c = gf * creg[t] + gi * gg;
            creg[t] = c;
            hout[(size_t)b_glob * 512 + bn * 8 + j_loc] = f2bf(go * c);  // no tanh on c
        }
        gbar(cnt + s, 64);
    }

    // final head (h final is in h0 after step 63)
    if (bn == 0 && w == 0) {
        int b = lane;
        const ushort* hrow = h0 + (size_t)b * 512;
        float acc = 0.f;
        for (int j = 0; j < 512; ++j) acc += bf2f(hrow[j]) * W_dec[j];
        float output = sigm(acc + b_dec[0]);
        float gate   = sigm(g_logit[b] * (1.0f / 64.f) + b_gate[0]);
        float ddp    = sigm(dd_logit[b] + b_dd[0]);
        out[b] = output * gate + ddp * (1.f - gate);
    }
}

extern "C" void kernel_launch(void* const* d_in, const int* in_sizes, int n_in,
                              void* d_out, int out_size, void* d_ws, size_t ws_size,
                              hipStream_t stream) {
    const float* v_feat   = (const float*)d_in[0];
    const int*   category = (const int*)d_in[1];
    const float* W_enc    = (const float*)d_in[2];
    const float* b_enc    = (const float*)d_in[3];
    const float* Wx       = (const float*)d_in[4];
    const float* bx       = (const float*)d_in[5];
    const float* Wh       = (const float*)d_in[6];
    const float* bh       = (const float*)d_in[7];
    const float* cat_emb  = (const float*)d_in[8];
    const float* W_dec    = (const float*)d_in[9];
    const float* b_dec    = (const float*)d_in[10];
    const float* proto    = (const float*)d_in[11];
    const float* W_dd     = (const float*)d_in[12];
    const float* b_dd     = (const float*)d_in[13];
    const float* W_gate   = (const float*)d_in[14];
    const float* b_gate   = (const float*)d_in[15];
    float* out = (float*)d_out;

    char* ws = (char*)d_ws;
    float*  xg       = (float*)(ws + 0);           // 32 MB [s][b][n']
    ushort* v_bf16   = (ushort*)(ws + 0);          // 16 MB (dead before GEMM2 writes xg)
    ushort* fuse     = (ushort*)(ws + 33554432);   // 4 MB bf16 [4096][512]
    ushort* Whr      = (ushort*)(ws + 37748736);   // 2 MB bf16 [2048][512] (j*4+g rows)
    ushort* Wenc_t   = (ushort*)(ws + 39845888);   // 2 MB bf16 [512][2048]
    ushort* Wx_t     = (ushort*)(ws + 41943040);   // 2 MB bf16 [2048][512]
    ushort* proto_bf = (ushort*)(ws + 44040192);   // 128 KB [32][2048] (rows 20..31 zero)
    float*  dots     = (float*)(ws + 44171264);    // 512 KB [4096][32]
    float*  n2       = (float*)(ws + 44695552);    // 16 KB
    float*  p2       = (float*)(ws + 44711936);    // 512 B reserved
    ushort* h0       = (ushort*)(ws + 44712448);   // 64 KB
    ushort* h1       = (ushort*)(ws + 44777984);   // 64 KB
    int*    cnt      = (int*)(ws + 44843520);      // 512 B
    float*  dd_logit = (float*)(ws + 44844032);    // 256 B
    float*  g_logit  = (float*)(ws + 44844288);    // 256 B

    hipMemsetAsync(proto_bf, 0, 131072, stream);
    hipMemsetAsync(h0, 0, 132096, stream);   // h0,h1,cnt,dd_logit,g_logit

    k_f32_to_bf16<<<8192, 256, 0, stream>>>(v_feat, v_bf16);
    k_f32_to_bf16<<<40, 256, 0, stream>>>(proto, proto_bf);
    k_transpose_bf16<<<dim3(16, 64), 256, 0, stream>>>(W_enc, Wenc_t, 2048, 512, 0);
    k_transpose_bf16<<<dim3(64, 16), 256, 0, stream>>>(Wx, Wx_t, 512, 2048, 0);
    k_transpose_bf16<<<dim3(64, 16), 256, 0, stream>>>(Wh, Whr, 512, 2048, 1);

    k_gemm_mfma<<<dim3(4, 32), 256, 0, stream>>>(v_bf16, Wenc_t, 4096, 512, 2048,
                                                 b_enc, nullptr, cat_emb, category,
                                                 fuse, 0);
    k_dot<<<64, 256, 0, stream>>>(v_bf16, proto_bf, dots);
    k_rowstats<<<1024, 256, 0, stream>>>(v_feat, W_gate, n2, g_logit);
    k_p2<<<20, 64, 0, stream>>>(proto, p2);
    k_dd<<<64, 256, 0, stream>>>(dots, n2, p2, W_dd, dd_logit);

    k_gemm_mfma<<<dim3(16, 32), 256, 0, stream>>>(fuse, Wx_t, 4096, 2048, 512,
                                                  bx, bh, nullptr, nullptr,
                                                  xg, 1);

    k_lstm_persist<<<64, 256, 0, stream>>>(xg, Whr, h0, h1, cnt,
                                           W_dec, b_dec, dd_logit, b_dd,
                                           g_logit, b_gate, out);
}